// Round 8
// baseline (333.533 us; speedup 1.0000x reference)
//
#include <hip/hip_runtime.h>

// PINNLayer — NN=100000, NE=3200000. fp32 in, fp32 out.
// d_out fp32: [ result (NN) | out2 (NE,3) rows = [src,dst,val] ].
//
// Round-13: r7 matched r1's best (327us). Remaining big item: accum_f (~90us,
// latency-bound, 35% occupancy, scalar record loads). Same algorithm, two
// mechanical fixes:
//  - edge_conv emits packed 8B streams recA={s,val}, recB={d,val*conc[s]}
//    (s==d encoded as node=0xFFFFFFFF -> matches no window; no consumer check).
//  - accum_ab: grid (224,2); each block owns ONE 64KB LDS table (A or B) ->
//    2 blocks/CU (2x occupancy), 448 blocks (all CUs busy); inner loop = one
//    coalesced uint2 load per record (4-way batched), window check, LDS atomic.
//    Load instrs per 4 records: 16 -> 4.
//   P1 edge_conv: LDS-tiled conv + out2 + recA/recB.
//   P2 accum_ab: 7 windows x 32 slices x {A,B}; flush = float4 partial stores.
//   P3 node_final_f: float4 x 4-nodes/thread reduce of 32 partials.
// Fallback to the proven round-5 pipeline if ws_size too small.

#define WSH  14
#define WSZ  16384      // nodes per window (64KB LDS table per pass)
#define PBF  32         // record slices (multiple of 8 for the XCD swizzle)

// old-path constants (fallback)
#define OWSH 13
#define OWSZ 8192
#define OPB  16
#define OFPS 8192.0f
#define OQBIAS (1 << 20)
#define OQCLMP ((1 << 19) - 1)

// ---------------------------------------------------------------------------
__global__ __launch_bounds__(256) void prep(
    const float* __restrict__ od,
    float* __restrict__ conc,
    unsigned long long* __restrict__ acc,
    int n_nodes)
{
    int n = blockIdx.x * blockDim.x + threadIdx.x;
    if (n >= n_nodes) return;
    conc[n] = od[(long long)n * 48 + 45];   // origin_data[n,15,0]
    if (acc) acc[n] = 0ULL;
}

// ---------------------------------------------------------------------------
// P1: LDS-tiled conv + out2 + packed record streams.
// val[e] = b + sum_{j<36} flow[e*12+j] * w_re[j],
//   w_re[kh*12+kw*4+i] = conv_w[i*9+kh*3+kw]
__global__ __launch_bounds__(256) void edge_conv(
    const float* __restrict__ flow, const int* __restrict__ ei,
    const float* __restrict__ conv_w, const float* __restrict__ conv_b,
    const float* __restrict__ conc,
    float* __restrict__ out2,
    uint2* __restrict__ recA, uint2* __restrict__ recB, int n_edges)
{
    __shared__ float w[40];
    __shared__ __align__(16) float4 stg[774];   // 258 rows x 3 float4 (12.4KB)

    const int t = threadIdx.x;
    if (t < 36) {
        int i  = t & 3;
        int kw = (t >> 2) % 3;
        int kh = t / 12;
        w[t] = conv_w[i * 9 + kh * 3 + kw];
    }
    if (t == 36) w[36] = conv_b[0];

    const long long E0 = (long long)blockIdx.x * 256;
    const long long e  = E0 + t;
    const bool live = (e < n_edges);

    // hoisted index + gather chains (independent of staging)
    int s = 0, d = 0;
    if (live) { s = ei[e]; d = ei[n_edges + e]; }
    float cs = live ? conc[s] : 0.f;            // L2-resident gather (400KB)

    // stage: rows E0..E0+257, consecutive coalesced float4 (each line ONCE)
    const long long rows_avail = (long long)n_edges + 2 - E0;  // flow has NE+2 rows
    const int nf4 = (int)(3 * (rows_avail < 258 ? rows_avail : 258));
    const float4* fb = (const float4*)flow + E0 * 3;
    for (int i = t; i < nf4; i += 256) stg[i] = fb[i];
    __syncthreads();

    if (!live) return;

    const float4* fp = &stg[t * 3];
    float acc = w[36];
#pragma unroll
    for (int q = 0; q < 9; ++q) {
        float4 v = fp[q];
        acc = fmaf(v.x, w[q * 4 + 0], acc);
        acc = fmaf(v.y, w[q * 4 + 1], acc);
        acc = fmaf(v.z, w[q * 4 + 2], acc);
        acc = fmaf(v.w, w[q * 4 + 3], acc);
    }

    float* o = out2 + e * 3;
    o[0] = (float)s;
    o[1] = (float)d;
    o[2] = acc;

    // self-edges get sentinel node (matches no window) -> no consumer check
    unsigned sk = (s == d) ? 0xFFFFFFFFu : (unsigned)s;
    unsigned dk = (s == d) ? 0xFFFFFFFFu : (unsigned)d;
    uint2 ra; ra.x = sk; ra.y = __float_as_uint(acc);
    uint2 rb; rb.x = dk; rb.y = __float_as_uint(acc * cs);
    recA[e] = ra;
    recB[e] = rb;
}

// ---------------------------------------------------------------------------
// P2: windowed LDS accumulation, one 64KB table per block (A xor B pass).
__global__ __launch_bounds__(1024) void accum_ab(
    const uint2* __restrict__ recA, const uint2* __restrict__ recB,
    float* __restrict__ pA, float* __restrict__ pB,
    int n_edges, int n_win, int stride)
{
    __shared__ float tbl[WSZ];      // 64KB -> 2 blocks/CU

    // XCD co-location on x (unchanged from proven r1 swizzle)
    const int xcd = blockIdx.x & 7;
    const int i   = blockIdx.x >> 3;
    const int j   = i / n_win;                 // 0 .. PBF/8-1
    const int sl  = xcd * (PBF >> 3) + j;      // slice id
    const int w   = i - j * n_win;             // window id

    const uint2* rec = blockIdx.y ? recB : recA;
    float*       par = blockIdx.y ? pB  : pA;

    const int t = threadIdx.x;
    for (int k = t; k < WSZ; k += 1024) tbl[k] = 0.f;
    __syncthreads();

    const long long e0 = (long long)sl * n_edges / PBF;
    const long long e1 = (long long)(sl + 1) * n_edges / PBF;

#define PROC(r)                                                        \
    if ((int)((r).x >> WSH) == w)                                      \
        atomicAdd(&tbl[(r).x & (WSZ - 1)], __uint_as_float((r).y));

    long long e = e0 + t;
    for (; e + 3 * 1024 < e1; e += 4 * 1024) {
        uint2 r0 = rec[e];
        uint2 r1 = rec[e + 1024];
        uint2 r2 = rec[e + 2048];
        uint2 r3 = rec[e + 3072];
        PROC(r0); PROC(r1); PROC(r2); PROC(r3);
    }
    for (; e < e1; e += 1024) {
        uint2 r = rec[e];
        PROC(r);
    }
#undef PROC
    __syncthreads();

    // Flush: plain coalesced float4 stores — no atomics.
    float* dst = par + (long long)sl * stride + ((long long)w << WSH);
    for (int k = t; k < (WSZ >> 2); k += 1024)
        ((float4*)dst)[k] = ((const float4*)tbl)[k];
}

// ---------------------------------------------------------------------------
// P3: vectorized reduce of PBF partials (4 nodes/thread, float4) + compose.
__global__ __launch_bounds__(256) void node_final_f(
    const float* __restrict__ od,
    const float* __restrict__ conc,
    const float* __restrict__ pA,
    const float* __restrict__ pB,
    float* __restrict__ out, int n_nodes, int stride)
{
    const int n0 = (blockIdx.x * 256 + threadIdx.x) * 4;
    if (n0 >= n_nodes) return;

    if (n0 + 4 <= n_nodes) {
        float4 a = make_float4(0.f, 0.f, 0.f, 0.f);
        float4 b = make_float4(0.f, 0.f, 0.f, 0.f);
#pragma unroll 8
        for (int sl = 0; sl < PBF; ++sl) {
            float4 va = *(const float4*)(pA + (size_t)sl * stride + n0);
            float4 vb = *(const float4*)(pB + (size_t)sl * stride + n0);
            a.x += va.x; a.y += va.y; a.z += va.z; a.w += va.w;
            b.x += vb.x; b.y += vb.y; b.z += vb.z; b.w += vb.w;
        }
        float4 c4 = *(const float4*)(conc + n0);
        float av[4] = {a.x, a.y, a.z, a.w};
        float bv[4] = {b.x, b.y, b.z, b.w};
        float cv[4] = {c4.x, c4.y, c4.z, c4.w};
        float rv[4];
#pragma unroll
        for (int j = 0; j < 4; ++j) {
            int n = n0 + j;
            long long bi = (long long)n * 48 + 45;
            float p  = od[bi + 1];
            float is = 1.0f / od[bi + 2];
            float r = cv[j];
            if (n != n_nodes - 1)
                r += (bv[j] - av[j] * cv[j]) * is + 0.0052f * p * is;
            rv[j] = r;
        }
        *(float4*)(out + n0) = make_float4(rv[0], rv[1], rv[2], rv[3]);
    } else {
        for (int n = n0; n < n_nodes; ++n) {
            float a = 0.f, b = 0.f;
#pragma unroll 8
            for (int sl = 0; sl < PBF; ++sl) {
                a += pA[(size_t)sl * stride + n];
                b += pB[(size_t)sl * stride + n];
            }
            long long bi = (long long)n * 48 + 45;
            float c  = conc[n];
            float p  = od[bi + 1];
            float is = 1.0f / od[bi + 2];
            float r = c;
            if (n != n_nodes - 1)
                r += (b - a * c) * is + 0.0052f * p * is;
            out[n] = r;
        }
    }
}

// ---------------------------------------------------------------------------
// Fallback path (round-5 proven): flat records + windowed scan + u64 atomics.
__global__ __launch_bounds__(256) void edge_conv_o(
    const float* __restrict__ flow, const int* __restrict__ ei,
    const float* __restrict__ conv_w, const float* __restrict__ conv_b,
    float* __restrict__ out2, int n_edges)
{
    __shared__ float w[40];
    int t = threadIdx.x;
    if (t < 36) {
        int i  = t & 3;
        int kw = (t >> 2) % 3;
        int kh = t / 12;
        w[t] = conv_w[i * 9 + kh * 3 + kw];
    }
    if (t == 36) w[36] = conv_b[0];
    __syncthreads();

    int e = blockIdx.x * blockDim.x + t;
    if (e >= n_edges) return;

    const float4* fp = (const float4*)(flow + (long long)e * 12);
    float acc = w[36];
#pragma unroll
    for (int q = 0; q < 9; ++q) {
        float4 v = fp[q];
        acc = fmaf(v.x, w[q * 4 + 0], acc);
        acc = fmaf(v.y, w[q * 4 + 1], acc);
        acc = fmaf(v.z, w[q * 4 + 2], acc);
        acc = fmaf(v.w, w[q * 4 + 3], acc);
    }

    float* o = out2 + (long long)e * 3;
    o[0] = (float)ei[e];
    o[1] = (float)ei[n_edges + e];
    o[2] = acc;
}

__global__ __launch_bounds__(1024) void accum_o(
    const float* __restrict__ out2,
    const float* __restrict__ conc,
    unsigned long long* __restrict__ acc,
    int n_edges, int n_nodes)
{
    __shared__ float tA[OWSZ];
    __shared__ float tB[OWSZ];

    const int w    = blockIdx.x / OPB;
    const int sl   = blockIdx.x % OPB;
    const int base = w << OWSH;

    for (int i = threadIdx.x; i < OWSZ; i += 1024) { tA[i] = 0.f; tB[i] = 0.f; }
    __syncthreads();

    const long long e0 = (long long)sl * n_edges / OPB;
    const long long e1 = (long long)(sl + 1) * n_edges / OPB;
    for (long long e = e0 + threadIdx.x; e < e1; e += 1024) {
        const float* r = out2 + e * 3;
        float fs = r[0], fd = r[1], v = r[2];
        int s = (int)fs, d = (int)fd;
        if (s == d) continue;
        if ((s >> OWSH) == w) atomicAdd(&tA[s - base], v);
        if ((d >> OWSH) == w) atomicAdd(&tB[d - base], v * conc[s]);
    }
    __syncthreads();

    for (int i = threadIdx.x; i < OWSZ; i += 1024) {
        int n = base + i;
        if (n >= n_nodes) continue;
        float a = tA[i], b = tB[i];
        if (a == 0.f && b == 0.f) continue;
        int qa = __float2int_rn(a * OFPS);
        int qb = __float2int_rn(b * OFPS);
        qa = min(max(qa, -OQCLMP), OQCLMP);
        qb = min(max(qb, -OQCLMP), OQCLMP);
        unsigned long long enc =
            ((unsigned long long)(unsigned)(qa + OQBIAS) << 37) +
            ((unsigned long long)(unsigned)(qb + OQBIAS) << 10) + 1ULL;
        atomicAdd(acc + n, enc);
    }
}

__global__ __launch_bounds__(256) void node_final_o(
    const float* __restrict__ od,
    const float* __restrict__ conc,
    const unsigned long long* __restrict__ acc,
    float* __restrict__ out, int n_nodes)
{
    int n = blockIdx.x * blockDim.x + threadIdx.x;
    if (n >= n_nodes) return;

    unsigned long long t = acc[n];
    long long cnt = (long long)(t & 1023ULL);
    unsigned long long t2 = t >> 10;
    long long sbr = (long long)(t2 & ((1ULL << 27) - 1));
    long long sar = (long long)(t2 >> 27);
    float a = (float)(sar - cnt * OQBIAS) * (1.0f / OFPS);
    float b = (float)(sbr - cnt * OQBIAS) * (1.0f / OFPS);

    long long bi = (long long)n * 48 + 45;
    float c  = conc[n];
    float p  = od[bi + 1];
    float is = 1.0f / od[bi + 2];

    float r = c;
    if (n != n_nodes - 1)
        r += (b - a * c) * is + 0.0052f * p * is;
    out[n] = r;
}

// ---------------------------------------------------------------------------
extern "C" void kernel_launch(void* const* d_in, const int* in_sizes, int n_in,
                              void* d_out, int out_size, void* d_ws, size_t ws_size,
                              hipStream_t stream) {
    const float* od   = (const float*)d_in[0];
    const float* flow = (const float*)d_in[1];
    const float* cw   = (const float*)d_in[2];
    const float* cb   = (const float*)d_in[3];
    const int*   ei   = (const int*)d_in[4];

    const int n_nodes = in_sizes[0] / 48;
    const int n_edges = in_sizes[4] / 2;

    float* out_res = (float*)d_out;        // (NN,)
    float* out2    = out_res + n_nodes;    // (NE,3)

    dim3 blk(256);
    dim3 grid_nodes((n_nodes + 255) / 256);

    // --- full-path workspace layout -------------------------------------
    const int n_win  = (n_nodes + WSZ - 1) >> WSH;     // 7
    const int stride = n_win << WSH;                   // padded node count
    size_t off = 0;
    size_t o_conc = off; off += (((size_t)n_nodes * 4) + 255) & ~255ULL;
    size_t o_rA   = off; off += (((size_t)n_edges * 8) + 255) & ~255ULL;
    size_t o_rB   = off; off += (((size_t)n_edges * 8) + 255) & ~255ULL;
    size_t o_pA   = off; off += (((size_t)PBF * stride * 4) + 255) & ~255ULL;
    size_t o_pB   = off; off += (((size_t)PBF * stride * 4) + 255) & ~255ULL;
    const bool full = (ws_size >= off);

    float* conc = (float*)((char*)d_ws + o_conc);

    if (full) {
        uint2* recA = (uint2*)((char*)d_ws + o_rA);
        uint2* recB = (uint2*)((char*)d_ws + o_rB);
        float* pA   = (float*)((char*)d_ws + o_pA);
        float* pB   = (float*)((char*)d_ws + o_pB);

        dim3 grid_ec((n_edges + 255) / 256);
        dim3 grid_nf(((n_nodes + 3) / 4 + 255) / 256);

        prep<<<grid_nodes, blk, 0, stream>>>(od, conc, nullptr, n_nodes);
        edge_conv<<<grid_ec, blk, 0, stream>>>(flow, ei, cw, cb, conc,
                                               out2, recA, recB, n_edges);
        accum_ab<<<dim3(n_win * PBF, 2), dim3(1024), 0, stream>>>(
            recA, recB, pA, pB, n_edges, n_win, stride);
        node_final_f<<<grid_nf, blk, 0, stream>>>(od, conc, pA, pB,
                                                  out_res, n_nodes, stride);
    } else {
        // round-5 pipeline
        unsigned long long* acc =
            (unsigned long long*)((char*)d_ws + (((size_t)n_nodes * 4 + 7) / 8 * 8));
        const int n_win_o = (n_nodes + OWSZ - 1) >> OWSH;
        dim3 grid_edges((n_edges + 255) / 256);

        prep<<<grid_nodes, blk, 0, stream>>>(od, conc, acc, n_nodes);
        edge_conv_o<<<grid_edges, blk, 0, stream>>>(flow, ei, cw, cb, out2, n_edges);
        accum_o<<<dim3(n_win_o * OPB), dim3(1024), 0, stream>>>(
            out2, conc, acc, n_edges, n_nodes);
        node_final_o<<<grid_nodes, blk, 0, stream>>>(od, conc, acc,
                                                     out_res, n_nodes);
    }
}